// Round 13
// baseline (137.693 us; speedup 1.0000x reference)
//
#include <hip/hip_runtime.h>
#include <stdint.h>

#define IMG 512
// Schraudolph scale (validated R4-R12, absmax 0.0039 vs thr 0.02):
// LDS holds q = p*KS2, KS2 = sqrt(50/ln2)*2^11.5 -> d^2 in exponent-field units
#define KS2     24598.990f
#define INV_KS2 4.0652061e-05f

#define TW  64     // tile output width (px)
#define TH  8      // tile rows
#define LWD 68     // staged cols (TW + 4 halo)
#define LW  69     // LDS row stride (dwords): odd & ==1 mod 4 -> wave row-groups
                   // on disjoint bank parities, stride-2 in-group = free 2-way
#define LH  12     // staged rows -> LDS = 12*69*4 = 3312 B

typedef float v2f  __attribute__((ext_vector_type(2)));
typedef int   v2i  __attribute__((ext_vector_type(2)));
typedef float v2fu __attribute__((ext_vector_type(2), aligned(4)));

__device__ __forceinline__ int reflect_idx(int g) {
    int a = abs(g);
    return min(a, 2 * IMG - 2 - a);
}

// Streaming regime (R2-proven: 85% VALUBusy at 80% occupancy): no register
// window,每 tap reads LDS directly (ds_read2_b32) and feeds packed asm math.
// Thread = 2 px (x-pair) in one row. Block (32,8) -> tile 64x8.
__global__ __launch_bounds__(256) void bilateral_main(
    const float* __restrict__ img, float* __restrict__ out)
{
    __shared__ float q[LH][LW];

    const int plane = blockIdx.z;
    const int x0 = 2 + blockIdx.x * TW;   // first output col (interior cols 2..509)
    const int y0 = blockIdx.y * TH;
    const float* __restrict__ src = img + (size_t)plane * (IMG * IMG);

    const int tx = threadIdx.x, ty = threadIdx.y;
    const int tid = tx + ty * 32;

    // Stage LH x LWD = 816 scaled elements (4 guarded passes).
    // Staged col c <-> global col (x0-2)+c; x-reflect unneeded for used range
    // (interior px only), reflect_idx still applied for safe OOB staging.
    #pragma unroll
    for (int p = 0; p < 4; ++p) {
        int idx = tid + p * 256;
        if (idx < LH * LWD) {
            int r = idx / LWD;            // magic-mul, no HW div
            int c = idx - r * LWD;
            q[r][c] = src[reflect_idx(y0 - 2 + r) * IMG
                          + reflect_idx(x0 - 2 + c)] * KS2;
        }
    }
    __syncthreads();

    // Last x-block covers 60 cols: mask tx >= 30 (after the barrier: safe).
    const int xp = x0 + 2 * tx;           // pair start col
    if (xp > 508) return;

    // Center pair (scaled): staged col 2+2tx, row ty+2.
    const float* cp = &q[ty + 2][2 * tx];
    v2f qc = *reinterpret_cast<const v2fu*>(cp + 2);

    v2f wsum = {1.0f, 1.0f};   // center tap: e = 1 exactly
    v2f acc  = qc;             // scaled-space accumulation

    #pragma unroll
    for (int dy = 0; dy < 5; ++dy) {
        const float* rp = &q[ty + dy][2 * tx];
        #pragma unroll
        for (int dx = 0; dx < 5; ++dx) {
            if (dy == 2 && dx == 2) continue;
            const int r2 = (dx - 2) * (dx - 2) + (dy - 2) * (dy - 2);
            // Ktap = float_bias + 2^23*log2(spatial_w) in exponent-field units
            const float    Kf    = (float)(1065353216.0 - 6051101.63118 * (double)r2);
            const uint32_t kb    = __builtin_bit_cast(uint32_t, Kf);
            const uint64_t kpair = (uint64_t)kb * 0x100000001ULL;  // both halves

            v2f qt = *reinterpret_cast<const v2fu*>(rp + dx);  // ds_read2_b32
            v2f d, t;
            // d = qt - qc
            asm("v_pk_add_f32 %0, %1, %2 neg_lo:[0,1] neg_hi:[0,1]"
                : "=v"(d) : "v"(qt), "v"(qc));
            // t = Ktap - d*d
            asm("v_pk_fma_f32 %0, %1, %1, %2 neg_lo:[1,0,0] neg_hi:[1,0,0]"
                : "=v"(t) : "v"(d), "s"(kpair));
            v2i iv = __builtin_convertvector(t, v2i);  // 2x v_cvt_i32_f32
            v2f e  = __builtin_bit_cast(v2f, iv);      // e ~ 2^arg (free bitcast)
            asm("v_pk_add_f32 %0, %1, %0" : "+v"(wsum) : "v"(e));
            asm("v_pk_fma_f32 %0, %1, %2, %0" : "+v"(acc) : "v"(e), "v"(qt));
        }
    }

    v2f res;
    res.x = acc.x * __builtin_amdgcn_rcpf(wsum.x) * INV_KS2;  // wsum >= 1
    res.y = acc.y * __builtin_amdgcn_rcpf(wsum.y) * INV_KS2;

    float* dst = out + (size_t)plane * (IMG * IMG) + (size_t)(y0 + ty) * IMG + xp;
    *reinterpret_cast<v2f*>(dst) = res;   // even col -> 8B-aligned dwordx2
}

// Edge kernel: columns {0,1,510,511} (0.8% of px), scalar with full reflect.
__global__ __launch_bounds__(256) void bilateral_edge(
    const float* __restrict__ img, float* __restrict__ out)
{
    const int idx = blockIdx.x * 256 + threadIdx.x;
    const int plane = idx >> 11;
    const int rem   = idx & 2047;
    const int y  = rem >> 2;
    const int xi = rem & 3;
    const int x  = (xi < 2) ? xi : (IMG - 4 + xi);   // 0,1,510,511

    const float* __restrict__ src = img + (size_t)plane * (IMG * IMG);
    const float qc = src[y * IMG + x];
    float wsum = 1.0f, acc = qc;

    #pragma unroll
    for (int dy = 0; dy < 5; ++dy) {
        const int yy = reflect_idx(y + dy - 2) * IMG;
        #pragma unroll
        for (int dx = 0; dx < 5; ++dx) {
            if (dy == 2 && dx == 2) continue;
            const int r2 = (dx - 2) * (dx - 2) + (dy - 2) * (dy - 2);
            const float Kf = (float)(1065353216.0 - 6051101.63118 * (double)r2);
            const float qt = src[yy + reflect_idx(x + dx - 2)];
            const float d  = (qt - qc) * KS2;
            const float t  = __builtin_fmaf(-d, d, Kf);
            const float e  = __builtin_bit_cast(float, (int)t);
            wsum += e;
            acc = __builtin_fmaf(e, qt, acc);
        }
    }
    out[(size_t)plane * (IMG * IMG) + y * IMG + x] = acc * __builtin_amdgcn_rcpf(wsum);
}

extern "C" void kernel_launch(void* const* d_in, const int* in_sizes, int n_in,
                              void* d_out, int out_size, void* d_ws, size_t ws_size,
                              hipStream_t stream) {
    const float* img = (const float*)d_in[0];
    float* out = (float*)d_out;
    const int planes = in_sizes[0] / (IMG * IMG);  // 48

    dim3 gmain((508 + TW - 1) / TW, IMG / TH, planes);  // (8, 64, 48)
    dim3 bmain(32, 8, 1);
    bilateral_main<<<gmain, bmain, 0, stream>>>(img, out);

    const int edge_threads = planes * IMG * 4;
    bilateral_edge<<<edge_threads / 256, 256, 0, stream>>>(img, out);
}

// Round 14
// 130.935 us; speedup vs baseline: 1.0516x; 1.0516x over previous
//
#include <hip/hip_runtime.h>
#include <stdint.h>

#define IMG 512
// Schraudolph scale (validated R4-R13, absmax 0.0039 vs thr 0.02):
// LDS holds q = p*KS2, KS2 = sqrt(50/ln2)*2^11.5, so exp(-50 d^2) ==
// bitcast(int(Ktap - dq^2)) with Ktap = bias + 2^23*log2(spatial_tap).
#define KS2     24598.990f
#define INV_KS2 4.0652061e-05f

#define TW 64     // tile width (px)
#define TH 16     // tile height (px)
#define LW 68     // LDS row stride = data width; wave reads are stride-1 ->
                  // 2-way half-wave bank alias only (free, m136)
#define LH 20     // staged rows; LDS = 20*68*4 = 5440 B

__device__ __forceinline__ int reflect_idx(int g) {
    int a = abs(g);
    return min(a, 2 * IMG - 2 - a);
}

// R2-proven streaming regime (85% VALUBusy / 80% occupancy / clean codegen):
// scalar math, 1 px at a time, LDS-direct tap reads, low VGPR, high TLP.
// All packed/asm variants (R4,R5,R11-R13) hit ~2x mov-marshaling bloat; this
// works WITH the compiler's preferred low-register streaming shape.
__global__ __launch_bounds__(256) void bilateral_kernel(
    const float* __restrict__ img, float* __restrict__ out)
{
    __shared__ float q[LH][LW];

    const int plane = blockIdx.z;
    const int x0 = blockIdx.x * TW;
    const int y0 = blockIdx.y * TH;
    const float* __restrict__ src = img + (size_t)plane * (IMG * IMG);

    const int tx = threadIdx.x, ty = threadIdx.y;   // block (64,4)

    // Stage 20 rows x 68 cols; pass p covers row ty + 4p (all passes full).
    #pragma unroll
    for (int p = 0; p < 5; ++p) {
        int r  = ty + 4 * p;
        int gr = reflect_idx(y0 - 2 + r) * IMG;
        q[r][tx] = src[gr + reflect_idx(x0 - 2 + tx)] * KS2;
        if (tx < 4)
            q[r][tx + 64] = src[gr + reflect_idx(x0 - 2 + tx + 64)] * KS2;
    }
    __syncthreads();

    float* dst = out + (size_t)plane * (IMG * IMG)
                     + (size_t)(y0 + ty) * IMG + (x0 + tx);

    // 4 pixels per thread at rows ty, ty+4, ty+8, ty+12 (matches staging).
    #pragma unroll
    for (int k = 0; k < 4; ++k) {
        const int row = ty + 4 * k;
        const float qc = q[row + 2][tx + 2];
        float wsum = 1.0f;          // center tap: e = 1 exactly
        float acc  = qc;            // scaled-space accumulation

        #pragma unroll
        for (int dy = 0; dy < 5; ++dy) {
            #pragma unroll
            for (int dx = 0; dx < 5; ++dx) {
                if (dy == 2 && dx == 2) continue;
                const int r2 = (dx - 2) * (dx - 2) + (dy - 2) * (dy - 2);
                const float Kf = (float)(1065353216.0 - 6051101.63118 * (double)r2);
                const float qt = q[row + dy][tx + dx];   // LDS scalar read
                const float d  = qt - qc;                // v_sub_f32
                const float t  = __builtin_fmaf(-d, d, Kf);   // v_fma_f32
                const float e  = __builtin_bit_cast(float, (int)t);  // v_cvt_i32_f32
                wsum += e;                               // v_add_f32
                acc  = __builtin_fmaf(e, qt, acc);       // v_fma_f32
            }
        }
        dst[(size_t)(4 * k) * IMG] = acc * __builtin_amdgcn_rcpf(wsum) * INV_KS2;
    }
}

extern "C" void kernel_launch(void* const* d_in, const int* in_sizes, int n_in,
                              void* d_out, int out_size, void* d_ws, size_t ws_size,
                              hipStream_t stream) {
    const float* img = (const float*)d_in[0];
    float* out = (float*)d_out;
    const int planes = in_sizes[0] / (IMG * IMG);  // 48

    dim3 grid(IMG / TW, IMG / TH, planes);   // (8, 32, 48)
    dim3 block(64, 4, 1);
    bilateral_kernel<<<grid, block, 0, stream>>>(img, out);
}